// Round 14
// baseline (279.912 us; speedup 1.0000x reference)
//
#include <hip/hip_runtime.h>
#include <math.h>

typedef __attribute__((ext_vector_type(8))) short bf16x8;
typedef __attribute__((ext_vector_type(4))) float f32x4;
typedef _Float16 half2v __attribute__((ext_vector_type(2)));
typedef _Float16 f16x8 __attribute__((ext_vector_type(8)));

__device__ __forceinline__ float silu(float x) {
    return x / (1.0f + __expf(-x));
}

__device__ __forceinline__ unsigned short f2bf(float x) {
    union { float f; unsigned u; } v; v.f = x;
    unsigned r = v.u + 0x7fffu + ((v.u >> 16) & 1u);   // RNE
    return (unsigned short)(r >> 16);
}

__device__ __forceinline__ unsigned pack2(float a, float b) {   // 2x bf16
    return (unsigned)f2bf(a) | ((unsigned)f2bf(b) << 16);
}

__device__ __forceinline__ unsigned pack2h(float a, float b) {  // 2x fp16
    half2v h; h[0] = (_Float16)a; h[1] = (_Float16)b;
    return __builtin_bit_cast(unsigned, h);
}

__device__ __forceinline__ unsigned cvt_pk(float lo, float hi) { // 2x bf16 RNE
    unsigned r;
    asm("v_cvt_pk_bf16_f32 %0, %1, %2" : "=v"(r) : "v"(lo), "v"(hi));
    return r;
}

// ---------------------------------------------------------------------------
// k_pre2 (fused): blocks [0,1024): SAB via MFMA; blocks [1024,1536): epk pack
// + agg zeroing (round-13 passing version, unchanged)
// ---------------------------------------------------------------------------
__global__ __launch_bounds__(256)
void k_pre2(const float* __restrict__ h_i,
            const float* __restrict__ np,
            const float* __restrict__ ep,
            const int* __restrict__ eidx,
            const float* __restrict__ W1, const float* __restrict__ b1,
            unsigned short* __restrict__ SAB,
            unsigned* __restrict__ epk,
            float* __restrict__ agg,
            int N, int E)
{
    if (blockIdx.x >= 1024) {
        const int tid = (blockIdx.x - 1024) * 256 + threadIdx.x;
        const int gs = 512 * 256;
        float4 z4 = make_float4(0.f, 0.f, 0.f, 0.f);
        for (int i = tid; i < N * 4; i += gs)
            ((float4*)agg)[i] = z4;
        for (int i = tid; i < E; i += gs)
            epk[i] = pack2h(ep[eidx[2 * i]], ep[eidx[2 * i + 1]]);  // faithful quirk
        return;
    }

    const int t = threadIdx.x;
    const int lane = t & 63;
    const int wv = t >> 6;
    const int lr = lane & 15;
    const int lq = lane >> 4;

    bf16x8 aw[4][3];
    #pragma unroll
    for (int mf = 0; mf < 4; ++mf) {
        const int c = wv * 64 + mf * 16 + lr;
        const bool isA = c < 128;
        const int col = c & 127;
        #pragma unroll
        for (int ks = 0; ks < 3; ++ks) {
            bf16x8 w;
            #pragma unroll
            for (int j = 0; j < 8; ++j) {
                const int kl = lq * 8 + j;
                float v = 0.0f;
                if (ks < 2) {
                    const int kk = ks * 32 + kl;
                    v = W1[(size_t)(isA ? kk : 64 + kk) * 128 + col];
                } else if (kl < 2) {
                    v = W1[(size_t)((isA ? 128 : 130) + kl) * 128 + col];
                }
                w[j] = (short)f2bf(v);
            }
            aw[mf][ks] = w;
        }
    }
    float4 b1v[4];
    #pragma unroll
    for (int mf = 0; mf < 4; ++mf) {
        if (wv < 2) b1v[mf] = *(const float4*)&b1[wv * 64 + mf * 16 + lq * 4];
        else        b1v[mf] = make_float4(0.f, 0.f, 0.f, 0.f);
    }

    const int nTiles = (N + 15) / 16;
    for (int tile = blockIdx.x; tile < nTiles; tile += 1024) {
        const int n  = tile * 16 + lr;
        const int nc = (n < N) ? n : (N - 1);

        const float* hr = h_i + (size_t)nc * 64;
        bf16x8 B0, B1, B2;
        {
            float4 a0 = *(const float4*)&hr[lq * 8];
            float4 a1 = *(const float4*)&hr[lq * 8 + 4];
            float4 a2 = *(const float4*)&hr[32 + lq * 8];
            float4 a3 = *(const float4*)&hr[32 + lq * 8 + 4];
            unsigned u[4];
            u[0] = pack2(a0.x, a0.y); u[1] = pack2(a0.z, a0.w);
            u[2] = pack2(a1.x, a1.y); u[3] = pack2(a1.z, a1.w);
            B0 = __builtin_bit_cast(bf16x8, *(uint4*)u);
            u[0] = pack2(a2.x, a2.y); u[1] = pack2(a2.z, a2.w);
            u[2] = pack2(a3.x, a3.y); u[3] = pack2(a3.z, a3.w);
            B1 = __builtin_bit_cast(bf16x8, *(uint4*)u);
            unsigned z[4] = {0u, 0u, 0u, 0u};
            if (lq == 0) z[0] = pack2(np[2 * nc], np[2 * nc + 1]);
            B2 = __builtin_bit_cast(bf16x8, *(uint4*)z);
        }

        f32x4 acc[4];
        #pragma unroll
        for (int mf = 0; mf < 4; ++mf) {
            acc[mf] = (f32x4){0.f, 0.f, 0.f, 0.f};
            acc[mf] = __builtin_amdgcn_mfma_f32_16x16x32_bf16(aw[mf][0], B0, acc[mf], 0, 0, 0);
            acc[mf] = __builtin_amdgcn_mfma_f32_16x16x32_bf16(aw[mf][1], B1, acc[mf], 0, 0, 0);
            acc[mf] = __builtin_amdgcn_mfma_f32_16x16x32_bf16(aw[mf][2], B2, acc[mf], 0, 0, 0);
        }

        if (n < N) {
            unsigned short* row = SAB + (size_t)n * 256;
            #pragma unroll
            for (int mf = 0; mf < 4; ++mf) {
                uint2 u;
                u.x = pack2h(acc[mf][0] + b1v[mf].x, acc[mf][1] + b1v[mf].y);
                u.y = pack2h(acc[mf][2] + b1v[mf].z, acc[mf][3] + b1v[mf].w);
                *(uint2*)&row[wv * 64 + mf * 16 + lq * 4] = u;
            }
        }
    }
}

// ---------------------------------------------------------------------------
// k_edge_v5: barrier-free, LDS-free (round-10/13 passing version, unchanged)
// ---------------------------------------------------------------------------
__global__ __launch_bounds__(256, 3)
void k_edge_v5(const unsigned short* __restrict__ SAB,  // [N][256] fp16
               const unsigned* __restrict__ epk,        // [E] fp16 pair
               const int* __restrict__ eidx,            // flat [2E]
               const float* __restrict__ W1,
               const float* __restrict__ W2, const float* __restrict__ b2,
               float* __restrict__ agg,
               int N, int E)
{
    const int t = threadIdx.x;
    const int lane = t & 63;
    const int wv = t >> 6;
    const int lr = lane & 15;
    const int lq = lane >> 4;

    half2v wA[4][4], wB[4][4];
    #pragma unroll
    for (int ks = 0; ks < 4; ++ks)
        #pragma unroll
        for (int c = 0; c < 4; ++c) {
            const int d = ks * 32 + lq * 8 + 2 * c;
            half2v a; a[0] = (_Float16)W1[132 * 128 + d]; a[1] = (_Float16)W1[132 * 128 + d + 1];
            half2v b; b[0] = (_Float16)W1[133 * 128 + d]; b[1] = (_Float16)W1[133 * 128 + d + 1];
            wA[ks][c] = a; wB[ks][c] = b;
        }

    bf16x8 bw2[4];
    #pragma unroll
    for (int ks = 0; ks < 4; ++ks) {
        bf16x8 w;
        #pragma unroll
        for (int j = 0; j < 8; ++j) {
            const int k = ks * 32 + lq * 8 + j;
            w[j] = (short)f2bf(W2[(size_t)k * 16 + lr]);
        }
        bw2[ks] = w;
    }
    const float bias2 = b2[lr];

    const uint4* S4 = (const uint4*)SAB;
    const int nG = (E + 15) / 16;
    const int gstride = gridDim.x * 4;
    int g = blockIdx.x * 4 + wv;
    if (g >= nG) return;

    int s0, r0; unsigned ep0; int rc0[4];
    uint4 A0[4], B0[4];
    {
        const int eb = g * 16;
        const int e = eb + lr; const int ec = (e < E) ? e : (E - 1);
        s0 = eidx[ec]; r0 = eidx[E + ec]; ep0 = epk[ec];
        if (eb + 16 <= E) {
            const int4 rv = *(const int4*)&eidx[E + eb + lq * 4];
            rc0[0] = rv.x; rc0[1] = rv.y; rc0[2] = rv.z; rc0[3] = rv.w;
        } else {
            #pragma unroll
            for (int r2 = 0; r2 < 4; ++r2) {
                int e4 = eb + lq * 4 + r2;
                rc0[r2] = eidx[E + ((e4 < E) ? e4 : (E - 1))];
            }
        }
        const uint4* pa = S4 + (size_t)s0 * 32;
        const uint4* pb = S4 + (size_t)r0 * 32 + 16;
        #pragma unroll
        for (int ks = 0; ks < 4; ++ks) { A0[ks] = pa[ks * 4 + lq]; B0[ks] = pb[ks * 4 + lq]; }
    }

    for (; g < nG; g += gstride) {
        const int gn = g + gstride;
        const bool hn = gn < nG;

        int s1 = 0, r1 = 0; unsigned ep1 = 0; int rc1[4] = {0, 0, 0, 0};
        if (hn) {
            const int eb = gn * 16;
            const int e = eb + lr; const int ec = (e < E) ? e : (E - 1);
            s1 = eidx[ec]; r1 = eidx[E + ec]; ep1 = epk[ec];
            if (eb + 16 <= E) {
                const int4 rv = *(const int4*)&eidx[E + eb + lq * 4];
                rc1[0] = rv.x; rc1[1] = rv.y; rc1[2] = rv.z; rc1[3] = rv.w;
            } else {
                #pragma unroll
                for (int r2 = 0; r2 < 4; ++r2) {
                    int e4 = eb + lq * 4 + r2;
                    rc1[r2] = eidx[E + ((e4 < E) ? e4 : (E - 1))];
                }
            }
        }

        const unsigned elo = (ep0 & 0xffffu) | (ep0 << 16);
        const unsigned ehi = (ep0 >> 16) | (ep0 & 0xffff0000u);
        const half2v e0 = __builtin_bit_cast(half2v, elo);
        const half2v e1 = __builtin_bit_cast(half2v, ehi);

        bf16x8 af[4];
        #pragma unroll
        for (int ks = 0; ks < 4; ++ks) {
            unsigned w[4];
            const unsigned* ua = (const unsigned*)&A0[ks];
            const unsigned* ub = (const unsigned*)&B0[ks];
            #pragma unroll
            for (int c = 0; c < 4; ++c) {
                half2v v = __builtin_bit_cast(half2v, ua[c])
                         + __builtin_bit_cast(half2v, ub[c]);
                v = wA[ks][c] * e0 + v;
                v = wB[ks][c] * e1 + v;
                const float x0 = (float)v[0];
                const float x1 = (float)v[1];
                w[c] = cvt_pk(silu(x0), silu(x1));
            }
            af[ks] = __builtin_bit_cast(bf16x8, *(uint4*)w);
        }

        uint4 A1[4], B1[4];
        if (hn) {
            const uint4* pa = S4 + (size_t)s1 * 32;
            const uint4* pb = S4 + (size_t)r1 * 32 + 16;
            #pragma unroll
            for (int ks = 0; ks < 4; ++ks) { A1[ks] = pa[ks * 4 + lq]; B1[ks] = pb[ks * 4 + lq]; }
        }

        f32x4 acc = (f32x4){0.f, 0.f, 0.f, 0.f};
        #pragma unroll
        for (int ks = 0; ks < 4; ++ks)
            acc = __builtin_amdgcn_mfma_f32_16x16x32_bf16(af[ks], bw2[ks], acc, 0, 0, 0);

        const int eb = g * 16;
        if (eb + 16 <= E) {
            #pragma unroll
            for (int r2 = 0; r2 < 4; ++r2)
                atomicAdd(&agg[(size_t)rc0[r2] * 16 + lr], silu(acc[r2] + bias2));
        } else {
            #pragma unroll
            for (int r2 = 0; r2 < 4; ++r2)
                if (eb + lq * 4 + r2 < E)
                    atomicAdd(&agg[(size_t)rc0[r2] * 16 + lr], silu(acc[r2] + bias2));
        }

        if (hn) {
            s0 = s1; r0 = r1; ep0 = ep1;
            #pragma unroll
            for (int r2 = 0; r2 < 4; ++r2) rc0[r2] = rc1[r2];
            #pragma unroll
            for (int ks = 0; ks < 4; ++ks) { A0[ks] = A1[ks]; B0[ks] = B1[ks]; }
        }
    }
}

// ---------------------------------------------------------------------------
// Jacobi machinery — per-node math identical to round-13 (4 sweeps).
// jrot2 interleaves two independent nodes' rotation chains for 2x ILP.
// ---------------------------------------------------------------------------
__host__ __device__ constexpr int tix(int i, int j) {
    return (i <= j) ? (i * 8 - (i * (i + 1)) / 2 + j)
                    : (j * 8 - (j * (j + 1)) / 2 + i);
}

template <int P, int Q>
__device__ __forceinline__ void jrot2(float* TA, float* VA, float* TB, float* VB) {
    const float appA = TA[tix(P, P)], aqqA = TA[tix(Q, Q)], apqA = TA[tix(P, Q)];
    const float appB = TB[tix(P, P)], aqqB = TB[tix(Q, Q)], apqB = TB[tix(P, Q)];

    float thA = (aqqA - appA) / (2.0f * apqA);
    float thB = (aqqB - appB) / (2.0f * apqB);
    float atA = fabsf(thA), atB = fabsf(thB);
    float ttA = 1.0f / (atA + sqrtf(atA * atA + 1.0f));
    float ttB = 1.0f / (atB + sqrtf(atB * atB + 1.0f));
    ttA = (thA < 0.0f) ? -ttA : ttA;
    ttB = (thB < 0.0f) ? -ttB : ttB;
    float ccA = __frsqrt_rn(ttA * ttA + 1.0f);
    float ccB = __frsqrt_rn(ttB * ttB + 1.0f);
    float ssA = ttA * ccA, ssB = ttB * ccB;

    const bool skA = !(fabsf(apqA) > 1e-36f);
    const bool skB = !(fabsf(apqB) > 1e-36f);
    const float cA = skA ? 1.0f : ccA, sA = skA ? 0.0f : ssA, tuA = skA ? 0.0f : ttA;
    const float cB = skB ? 1.0f : ccB, sB = skB ? 0.0f : ssB, tuB = skB ? 0.0f : ttB;

    #pragma unroll
    for (int k = 0; k < 8; ++k) {
        if (k == P || k == Q) continue;
        const float akpA = TA[tix(k, P)], akqA = TA[tix(k, Q)];
        TA[tix(k, P)] = cA * akpA - sA * akqA;
        TA[tix(k, Q)] = sA * akpA + cA * akqA;
        const float akpB = TB[tix(k, P)], akqB = TB[tix(k, Q)];
        TB[tix(k, P)] = cB * akpB - sB * akqB;
        TB[tix(k, Q)] = sB * akpB + cB * akqB;
    }
    TA[tix(P, P)] = appA - tuA * apqA;
    TA[tix(Q, Q)] = aqqA + tuA * apqA;
    TA[tix(P, Q)] = 0.0f;
    TB[tix(P, P)] = appB - tuB * apqB;
    TB[tix(Q, Q)] = aqqB + tuB * apqB;
    TB[tix(P, Q)] = 0.0f;

    #pragma unroll
    for (int k = 0; k < 8; ++k) {
        const float vpA = VA[k * 8 + P], vqA = VA[k * 8 + Q];
        VA[k * 8 + P] = cA * vpA - sA * vqA;
        VA[k * 8 + Q] = sA * vpA + cA * vqA;
        const float vpB = VB[k * 8 + P], vqB = VB[k * 8 + Q];
        VB[k * 8 + P] = cB * vpB - sB * vqB;
        VB[k * 8 + Q] = sB * vpB + cB * vqB;
    }
}

__device__ __forceinline__ void jacobi_sweep2(float* TA, float* VA,
                                              float* TB, float* VB) {
    jrot2<0,1>(TA,VA,TB,VB); jrot2<0,2>(TA,VA,TB,VB); jrot2<0,3>(TA,VA,TB,VB);
    jrot2<0,4>(TA,VA,TB,VB); jrot2<0,5>(TA,VA,TB,VB); jrot2<0,6>(TA,VA,TB,VB);
    jrot2<0,7>(TA,VA,TB,VB);
    jrot2<1,2>(TA,VA,TB,VB); jrot2<1,3>(TA,VA,TB,VB); jrot2<1,4>(TA,VA,TB,VB);
    jrot2<1,5>(TA,VA,TB,VB); jrot2<1,6>(TA,VA,TB,VB); jrot2<1,7>(TA,VA,TB,VB);
    jrot2<2,3>(TA,VA,TB,VB); jrot2<2,4>(TA,VA,TB,VB); jrot2<2,5>(TA,VA,TB,VB);
    jrot2<2,6>(TA,VA,TB,VB); jrot2<2,7>(TA,VA,TB,VB);
    jrot2<3,4>(TA,VA,TB,VB); jrot2<3,5>(TA,VA,TB,VB); jrot2<3,6>(TA,VA,TB,VB);
    jrot2<3,7>(TA,VA,TB,VB);
    jrot2<4,5>(TA,VA,TB,VB); jrot2<4,6>(TA,VA,TB,VB); jrot2<4,7>(TA,VA,TB,VB);
    jrot2<5,6>(TA,VA,TB,VB); jrot2<5,7>(TA,VA,TB,VB);
    jrot2<6,7>(TA,VA,TB,VB);
}

#define CSWAPG(eig, V, a, b)                                                 \
    {                                                                        \
        bool sw = eig[a] > eig[b];                                           \
        float lo = sw ? eig[b] : eig[a];                                     \
        float hi = sw ? eig[a] : eig[b];                                     \
        eig[a] = lo; eig[b] = hi;                                            \
        _Pragma("unroll")                                                    \
        for (int k = 0; k < 8; ++k) {                                        \
            float va = V[k * 8 + a], vb = V[k * 8 + b];                      \
            V[k * 8 + a] = sw ? vb : va;                                     \
            V[k * 8 + b] = sw ? va : vb;                                     \
        }                                                                    \
    }

#define SORT8(eig, V)                                                        \
    CSWAPG(eig,V,0,1) CSWAPG(eig,V,2,3) CSWAPG(eig,V,4,5) CSWAPG(eig,V,6,7)  \
    CSWAPG(eig,V,0,2) CSWAPG(eig,V,1,3) CSWAPG(eig,V,4,6) CSWAPG(eig,V,5,7)  \
    CSWAPG(eig,V,1,2) CSWAPG(eig,V,5,6)                                      \
    CSWAPG(eig,V,0,4) CSWAPG(eig,V,1,5) CSWAPG(eig,V,2,6) CSWAPG(eig,V,3,7)  \
    CSWAPG(eig,V,2,4) CSWAPG(eig,V,3,5)                                      \
    CSWAPG(eig,V,1,2) CSWAPG(eig,V,3,4) CSWAPG(eig,V,5,6)

// ---------------------------------------------------------------------------
// k_node2x: 2 nodes/thread (ILP-2 Jacobi), 128-thread blocks covering 256
// nodes. Node-B state stashed in LDS during node-A's MLP pass.
// ---------------------------------------------------------------------------
__global__ __launch_bounds__(128)
void k_node2x(const float* __restrict__ h_i,
              const float* __restrict__ agg,
              const float* __restrict__ W3, const float* __restrict__ b3,
              const float* __restrict__ W4, const float* __restrict__ b4,
              float* __restrict__ out, int N)
{
    __shared__ _Float16 fl[2][64][40];
    __shared__ _Float16 hl[2][16][136];
    __shared__ float    zl[2][64][8];
    __shared__ float    vstash[128][65];
    __shared__ float    estash[128][9];

    const int t = threadIdx.x;      // 0..127
    const int lane = t & 63;
    const int wv = t >> 6;          // 0..1
    const int lr = lane & 15;
    const int lq = lane >> 4;

    const int nA  = blockIdx.x * 256 + t;
    const int nB  = nA + 128;
    const int ncA = (nA < N) ? nA : (N - 1);
    const int ncB = (nB < N) ? nB : (N - 1);

    // ---- dual Jacobi (4 sweeps, interleaved chains) ----
    float TA[36], VA[64], TB[36], VB[64];
    {
        float A[64];
        const float4* src = (const float4*)(h_i + (size_t)ncA * 64);
        #pragma unroll
        for (int i = 0; i < 16; ++i) ((float4*)A)[i] = src[i];
        #pragma unroll
        for (int i = 0; i < 8; ++i)
            #pragma unroll
            for (int j = 0; j < 8; ++j)
                if (i <= j) TA[tix(i, j)] = A[i * 8 + j];
    }
    {
        float A[64];
        const float4* src = (const float4*)(h_i + (size_t)ncB * 64);
        #pragma unroll
        for (int i = 0; i < 16; ++i) ((float4*)A)[i] = src[i];
        #pragma unroll
        for (int i = 0; i < 8; ++i)
            #pragma unroll
            for (int j = 0; j < 8; ++j)
                if (i <= j) TB[tix(i, j)] = A[i * 8 + j];
    }
    #pragma unroll
    for (int i = 0; i < 64; ++i) { VA[i] = 0.0f; VB[i] = 0.0f; }
    #pragma unroll
    for (int i = 0; i < 8; ++i) { VA[i * 8 + i] = 1.0f; VB[i * 8 + i] = 1.0f; }

    #pragma unroll 1
    for (int sw = 0; sw < 4; ++sw) jacobi_sweep2(TA, VA, TB, VB);

    float eigA[8], eigB[8];
    #pragma unroll
    for (int i = 0; i < 8; ++i) { eigA[i] = TA[tix(i, i)]; eigB[i] = TB[tix(i, i)]; }

    SORT8(eigA, VA)
    SORT8(eigB, VB)

    // stash node-B state to LDS (own slot; no cross-thread access)
    #pragma unroll
    for (int i = 0; i < 64; ++i) vstash[t][i] = VB[i];
    #pragma unroll
    for (int i = 0; i < 8; ++i) estash[t][i] = eigB[i];

    // ---- W3/W4 f16 fragments (persist across both MLP passes) ----
    f16x8 w3f[8];
    #pragma unroll
    for (int nf = 0; nf < 8; ++nf) {
        f16x8 w;
        #pragma unroll
        for (int j = 0; j < 8; ++j)
            w[j] = (_Float16)W3[(size_t)(lq * 8 + j) * 128 + nf * 16 + lr];
        w3f[nf] = w;
    }
    f16x8 w4f[4];
    #pragma unroll
    for (int ks = 0; ks < 4; ++ks) {
        f16x8 w;
        #pragma unroll
        for (int j = 0; j < 8; ++j)
            w[j] = (lr < 8) ? (_Float16)W4[(size_t)(ks * 32 + lq * 8 + j) * 8 + lr]
                            : (_Float16)0.0f;
        w4f[ks] = w;
    }
    float b3v[8];
    #pragma unroll
    for (int nf = 0; nf < 8; ++nf) b3v[nf] = b3[nf * 16 + lr];
    const float b4v = (lr < 8) ? b4[lr] : 0.0f;

    // ================= pass A, then pass B =================
    #pragma unroll 1
    for (int pass = 0; pass < 2; ++pass) {
        const int n  = pass ? nB : nA;
        const int nc = pass ? ncB : ncA;
        float* V   = VA;        // VA reused as working V for both passes
        float* eig = eigA;
        if (pass) {
            // reload node-B state from LDS
            #pragma unroll
            for (int i = 0; i < 64; ++i) V[i] = vstash[t][i];
            #pragma unroll
            for (int i = 0; i < 8; ++i) eig[i] = estash[t][i];
        }

        // feats = [agg(16) | eig(8) | 1.0 x8] -> LDS (f16)
        {
            float f[32];
            const float4* ag = (const float4*)(agg + (size_t)nc * 16);
            #pragma unroll
            for (int i = 0; i < 4; ++i) {
                float4 v = ag[i];
                f[i * 4 + 0] = v.x; f[i * 4 + 1] = v.y;
                f[i * 4 + 2] = v.z; f[i * 4 + 3] = v.w;
            }
            #pragma unroll
            for (int i = 0; i < 8; ++i) f[16 + i] = eig[i];
            #pragma unroll
            for (int i = 0; i < 8; ++i) f[24 + i] = 1.0f;

            unsigned* dst = (unsigned*)&fl[wv][lane][0];
            #pragma unroll
            for (int i = 0; i < 16; ++i) dst[i] = pack2h(f[2 * i], f[2 * i + 1]);
        }
        __syncthreads();

        #pragma unroll 1
        for (int b = 0; b < 4; ++b) {
            const f16x8 a1 = *(const f16x8*)&fl[wv][b * 16 + lr][lq * 8];
            f32x4 acc1[8];
            #pragma unroll
            for (int nf = 0; nf < 8; ++nf) {
                acc1[nf] = (f32x4){0.f, 0.f, 0.f, 0.f};
                acc1[nf] = __builtin_amdgcn_mfma_f32_16x16x32_f16(a1, w3f[nf], acc1[nf], 0, 0, 0);
            }
            #pragma unroll
            for (int nf = 0; nf < 8; ++nf)
                #pragma unroll
                for (int r2 = 0; r2 < 4; ++r2) {
                    const float x = acc1[nf][r2] + b3v[nf];
                    hl[wv][lq * 4 + r2][nf * 16 + lr] = (_Float16)silu(x);
                }
            __syncthreads();

            f32x4 acc2 = (f32x4){0.f, 0.f, 0.f, 0.f};
            #pragma unroll
            for (int ks = 0; ks < 4; ++ks) {
                const f16x8 a2 = *(const f16x8*)&hl[wv][lr][ks * 32 + lq * 8];
                acc2 = __builtin_amdgcn_mfma_f32_16x16x32_f16(a2, w4f[ks], acc2, 0, 0, 0);
            }
            if (lr < 8) {
                #pragma unroll
                for (int r2 = 0; r2 < 4; ++r2)
                    zl[wv][b * 16 + lq * 4 + r2][lr] = acc2[r2] + b4v;
            }
            __syncthreads();
        }

        float z[8];
        {
            float4 z0 = *(const float4*)&zl[wv][lane][0];
            float4 z1 = *(const float4*)&zl[wv][lane][4];
            z[0] = z0.x; z[1] = z0.y; z[2] = z0.z; z[3] = z0.w;
            z[4] = z1.x; z[5] = z1.y; z[6] = z1.z; z[7] = z1.w;
        }
        float m = z[0];
        #pragma unroll
        for (int o = 1; o < 8; ++o) m = fmaxf(m, z[o]);
        float lam[8], den = 0.0f;
        #pragma unroll
        for (int o = 0; o < 8; ++o) { lam[o] = __expf(z[o] - m); den += lam[o]; }
        const float inv = 1.0f / den;
        #pragma unroll
        for (int o = 0; o < 8; ++o) lam[o] *= inv;

        if (n < N) {
            float* orow = out + (size_t)n * 64;
            #pragma unroll
            for (int i = 0; i < 8; ++i) {
                float si[8];
                #pragma unroll
                for (int j = 0; j < 8; ++j) si[j] = lam[j] * V[i * 8 + j];
                float r[8];
                #pragma unroll
                for (int k = 0; k < 8; ++k) {
                    float sum = 0.0f;
                    #pragma unroll
                    for (int j = 0; j < 8; ++j) sum += si[j] * V[k * 8 + j];
                    r[k] = sum;
                }
                ((float4*)orow)[i * 2 + 0] = make_float4(r[0], r[1], r[2], r[3]);
                ((float4*)orow)[i * 2 + 1] = make_float4(r[4], r[5], r[6], r[7]);
            }
        }
        __syncthreads();   // all zl reads done before next pass overwrites fl
    }
}

// ---------------------------------------------------------------------------
// Fallback edge kernel (round-2 style, raw fp32 inputs, needs only agg in ws)
// ---------------------------------------------------------------------------
#define CATS 168
#define HS   136
__global__ __launch_bounds__(256, 2)
void k_edge_v2(const float* __restrict__ h_i,
               const float* __restrict__ node_params,
               const float* __restrict__ edge_params,
               const float* __restrict__ W1, const float* __restrict__ b1,
               const float* __restrict__ W2, const float* __restrict__ b2,
               const int* __restrict__ eidx,
               float* __restrict__ agg,
               int N, int E)
{
    __shared__ unsigned short smem[23680];
    unsigned short* w1t = smem;
    unsigned short* w2t = smem + 128 * CATS;
    unsigned short* cat = smem;
    unsigned short* hid = smem + 64 * CATS;

    const int t = threadIdx.x;
    const int lane = t & 63;
    const int wv = t >> 6;
    const int wn = wv & 1;
    const int wm = wv >> 1;
    const int lr = lane & 15;
    const int lq = lane >> 4;

    for (int idx = t; idx < 128 * 80; idx += 256) {
        const int col = idx & 127, kp = idx >> 7;
        const int k0 = 2 * kp;
        float f0 = (k0     < 134) ? W1[(size_t)k0       * 128 + col] : 0.0f;
        float f1 = (k0 + 1 < 134) ? W1[(size_t)(k0 + 1) * 128 + col] : 0.0f;
        *(unsigned*)&w1t[col * CATS + k0] = pack2(f0, f1);
    }
    for (int idx = t; idx < 16 * 64; idx += 256) {
        const int col = idx & 15, kp = idx >> 4;
        const int k0 = 2 * kp;
        *(unsigned*)&w2t[col * HS + k0] =
            pack2(W2[(size_t)k0 * 16 + col], W2[(size_t)(k0 + 1) * 16 + col]);
    }
    __syncthreads();

    bf16x8 bw1[4][5];
    #pragma unroll
    for (int nf = 0; nf < 4; ++nf)
        #pragma unroll
        for (int ks = 0; ks < 5; ++ks)
            bw1[nf][ks] = *(const bf16x8*)&w1t[(wn * 64 + nf * 16 + lr) * CATS + ks * 32 + lq * 8];
    bf16x8 bw2[4];
    #pragma unroll
    for (int ks = 0; ks < 4; ++ks)
        bw2[ks] = *(const bf16x8*)&w2t[lr * HS + ks * 32 + lq * 8];

    float bias1[4];
    #pragma unroll
    for (int nf = 0; nf < 4; ++nf) bias1[nf] = b1[wn * 64 + nf * 16 + lr];
    const float bias2 = b2[lr];
    __syncthreads();

    const int el = t >> 2;
    const int p  = t & 3;

    const int nTiles = E / 64;
    for (int tile = blockIdx.x; tile < nTiles; tile += gridDim.x) {
        const int ebase = tile * 64;
        {
            const int eg  = ebase + el;
            const int egc = (eg < E) ? eg : (E - 1);
            const int s = eidx[egc];
            const int r = eidx[E + egc];
            const float4* hs = (const float4*)(h_i + (size_t)s * 64);
            const float4* hr = (const float4*)(h_i + (size_t)r * 64);
            unsigned short* crow = cat + el * CATS;
            #pragma unroll
            for (int m = 0; m < 8; ++m) {
                const int q = p + 4 * m;
                float4 v = (q < 16) ? hs[q] : hr[q - 16];
                uint2 u; u.x = pack2(v.x, v.y); u.y = pack2(v.z, v.w);
                *(uint2*)&crow[q * 4] = u;
            }
            if (p == 0) {
                const int i0 = eidx[2 * egc];
                const int i1 = eidx[2 * egc + 1];
                uint4 u;
                u.x = pack2(node_params[2 * s], node_params[2 * s + 1]);
                u.y = pack2(node_params[2 * r], node_params[2 * r + 1]);
                u.z = pack2(edge_params[i0], edge_params[i1]);
                u.w = 0u;
                *(uint4*)&crow[128] = u;
            } else {
                uint4 z; z.x = z.y = z.z = z.w = 0u;
                *(uint4*)&crow[136 + (p - 1) * 8] = z;
            }
        }
        __syncthreads();

        f32x4 acc[2][4];
        #pragma unroll
        for (int mf = 0; mf < 2; ++mf)
            #pragma unroll
            for (int nf = 0; nf < 4; ++nf)
                acc[mf][nf] = (f32x4){0.f, 0.f, 0.f, 0.f};

        const unsigned short* pa = cat + (wm * 32 + lr) * CATS + lq * 8;
        #pragma unroll
        for (int ks = 0; ks < 5; ++ks) {
            const bf16x8 a0 = *(const bf16x8*)(pa + ks * 32);
            const bf16x8 a1 = *(const bf16x8*)(pa + 16 * CATS + ks * 32);
            #pragma unroll
            for (int nf = 0; nf < 4; ++nf) {
                acc[0][nf] = __builtin_amdgcn_mfma_f32_16x16x32_bf16(a0, bw1[nf][ks], acc[0][nf], 0, 0, 0);
                acc[1][nf] = __builtin_amdgcn_mfma_f32_16x16x32_bf16(a1, bw1[nf][ks], acc[1][nf], 0, 0, 0);
            }
        }
        __syncthreads();

        #pragma unroll
        for (int mf = 0; mf < 2; ++mf)
            #pragma unroll
            for (int nf = 0; nf < 4; ++nf) {
                const float bb = bias1[nf];
                #pragma unroll
                for (int r2 = 0; r2 < 4; ++r2) {
                    const float x = acc[mf][nf][r2] + bb;
                    hid[(wm * 32 + mf * 16 + lq * 4 + r2) * HS + wn * 64 + nf * 16 + lr] =
                        f2bf(silu(x));
                }
            }
        __syncthreads();

        f32x4 acc2 = (f32x4){0.f, 0.f, 0.f, 0.f};
        const unsigned short* ph = hid + (wv * 16 + lr) * HS + lq * 8;
        #pragma unroll
        for (int ks = 0; ks < 4; ++ks)
            acc2 = __builtin_amdgcn_mfma_f32_16x16x32_bf16(
                *(const bf16x8*)(ph + ks * 32), bw2[ks], acc2, 0, 0, 0);

        #pragma unroll
        for (int r2 = 0; r2 < 4; ++r2) {
            const int eg2 = ebase + wv * 16 + lq * 4 + r2;
            if (eg2 < E) {
                const int rcv = eidx[E + eg2];
                const float v = silu(acc2[r2] + bias2);
                atomicAdd(&agg[(size_t)rcv * 16 + lr], v);
            }
        }
        __syncthreads();
    }
}

// ---------------------------------------------------------------------------
extern "C" void kernel_launch(void* const* d_in, const int* in_sizes, int n_in,
                              void* d_out, int out_size, void* d_ws, size_t ws_size,
                              hipStream_t stream) {
    const float* h_i  = (const float*)d_in[0];
    const float* npar = (const float*)d_in[1];
    const float* epar = (const float*)d_in[2];
    const float* W1   = (const float*)d_in[3];
    const float* b1   = (const float*)d_in[4];
    const float* W2   = (const float*)d_in[5];
    const float* b2   = (const float*)d_in[6];
    const float* W3   = (const float*)d_in[7];
    const float* b3   = (const float*)d_in[8];
    const float* W4   = (const float*)d_in[9];
    const float* b4   = (const float*)d_in[10];
    const int*   eidx = (const int*)d_in[11];

    const int N = in_sizes[0] / 64;
    const int E = in_sizes[11] / 2;

    // workspace layout: agg | SAB(fp16 N x 256) | epk
    const size_t aggB = (size_t)N * 16 * sizeof(float);
    size_t off = (aggB + 255) & ~(size_t)255;
    const size_t sabOff = off;                  off += (size_t)N * 256 * 2;
    off = (off + 255) & ~(size_t)255;
    const size_t epkOff = off;                  off += (size_t)E * 4;
    const size_t need = off;

    float* agg = (float*)d_ws;

    if (ws_size >= need) {
        unsigned short* SAB = (unsigned short*)((char*)d_ws + sabOff);
        unsigned* epk = (unsigned*)((char*)d_ws + epkOff);

        k_pre2<<<1536, 256, 0, stream>>>(h_i, npar, epar, eidx, W1, b1,
                                         SAB, epk, agg, N, E);
        k_edge_v5<<<2048, 256, 0, stream>>>(SAB, epk, eidx, W1, W2, b2,
                                            agg, N, E);
    } else {
        (void)hipMemsetAsync(agg, 0, aggB, stream);
        int blocks = E / 64;
        if (blocks > 768) blocks = 768;
        k_edge_v2<<<blocks, 256, 0, stream>>>(h_i, npar, epar, W1, b1, W2, b2,
                                              eidx, agg, N, E);
    }
    k_node2x<<<(N + 255) / 256, 128, 0, stream>>>(h_i, agg, W3, b3, W4, b4,
                                                  (float*)d_out, N);
}

// Round 15
// 263.276 us; speedup vs baseline: 1.0632x; 1.0632x over previous
//
#include <hip/hip_runtime.h>
#include <math.h>

typedef __attribute__((ext_vector_type(8))) short bf16x8;
typedef __attribute__((ext_vector_type(4))) float f32x4;
typedef _Float16 half2v __attribute__((ext_vector_type(2)));
typedef _Float16 f16x8 __attribute__((ext_vector_type(8)));

__device__ __forceinline__ float silu(float x) {
    return x / (1.0f + __expf(-x));
}

__device__ __forceinline__ unsigned short f2bf(float x) {
    union { float f; unsigned u; } v; v.f = x;
    unsigned r = v.u + 0x7fffu + ((v.u >> 16) & 1u);   // RNE
    return (unsigned short)(r >> 16);
}

__device__ __forceinline__ unsigned pack2(float a, float b) {   // 2x bf16
    return (unsigned)f2bf(a) | ((unsigned)f2bf(b) << 16);
}

__device__ __forceinline__ unsigned pack2h(float a, float b) {  // 2x fp16
    half2v h; h[0] = (_Float16)a; h[1] = (_Float16)b;
    return __builtin_bit_cast(unsigned, h);
}

__device__ __forceinline__ unsigned cvt_pk(float lo, float hi) { // 2x bf16 RNE
    unsigned r;
    asm("v_cvt_pk_bf16_f32 %0, %1, %2" : "=v"(r) : "v"(lo), "v"(hi));
    return r;
}

// ---------------------------------------------------------------------------
// k_pre2 (fused): blocks [0,896): SAB via MFMA; blocks [896,1536): epk pack
// + agg zeroing. (Round-13 passing code; split rebalanced 1024/512 -> 896/640
// since the aux leg was the longer one.)
//   SA[n] = h[n]@W1[0:64]   + np[n]@W1[128:130] + b1
//   SB[n] = h[n]@W1[64:128] + np[n]@W1[130:132]
// ---------------------------------------------------------------------------
#define PRE_MFMA_B 896
#define PRE_AUX_B  640
__global__ __launch_bounds__(256)
void k_pre2(const float* __restrict__ h_i,
            const float* __restrict__ np,
            const float* __restrict__ ep,
            const int* __restrict__ eidx,
            const float* __restrict__ W1, const float* __restrict__ b1,
            unsigned short* __restrict__ SAB,
            unsigned* __restrict__ epk,
            float* __restrict__ agg,
            int N, int E)
{
    if (blockIdx.x >= PRE_MFMA_B) {
        const int tid = (blockIdx.x - PRE_MFMA_B) * 256 + threadIdx.x;
        const int gs = PRE_AUX_B * 256;
        float4 z4 = make_float4(0.f, 0.f, 0.f, 0.f);
        for (int i = tid; i < N * 4; i += gs)
            ((float4*)agg)[i] = z4;
        for (int i = tid; i < E; i += gs)
            epk[i] = pack2h(ep[eidx[2 * i]], ep[eidx[2 * i + 1]]);  // faithful quirk
        return;
    }

    const int t = threadIdx.x;
    const int lane = t & 63;
    const int wv = t >> 6;
    const int lr = lane & 15;
    const int lq = lane >> 4;

    bf16x8 aw[4][3];
    #pragma unroll
    for (int mf = 0; mf < 4; ++mf) {
        const int c = wv * 64 + mf * 16 + lr;
        const bool isA = c < 128;
        const int col = c & 127;
        #pragma unroll
        for (int ks = 0; ks < 3; ++ks) {
            bf16x8 w;
            #pragma unroll
            for (int j = 0; j < 8; ++j) {
                const int kl = lq * 8 + j;
                float v = 0.0f;
                if (ks < 2) {
                    const int kk = ks * 32 + kl;
                    v = W1[(size_t)(isA ? kk : 64 + kk) * 128 + col];
                } else if (kl < 2) {
                    v = W1[(size_t)((isA ? 128 : 130) + kl) * 128 + col];
                }
                w[j] = (short)f2bf(v);
            }
            aw[mf][ks] = w;
        }
    }
    float4 b1v[4];
    #pragma unroll
    for (int mf = 0; mf < 4; ++mf) {
        if (wv < 2) b1v[mf] = *(const float4*)&b1[wv * 64 + mf * 16 + lq * 4];
        else        b1v[mf] = make_float4(0.f, 0.f, 0.f, 0.f);
    }

    const int nTiles = (N + 15) / 16;
    for (int tile = blockIdx.x; tile < nTiles; tile += PRE_MFMA_B) {
        const int n  = tile * 16 + lr;
        const int nc = (n < N) ? n : (N - 1);

        const float* hr = h_i + (size_t)nc * 64;
        bf16x8 B0, B1, B2;
        {
            float4 a0 = *(const float4*)&hr[lq * 8];
            float4 a1 = *(const float4*)&hr[lq * 8 + 4];
            float4 a2 = *(const float4*)&hr[32 + lq * 8];
            float4 a3 = *(const float4*)&hr[32 + lq * 8 + 4];
            unsigned u[4];
            u[0] = pack2(a0.x, a0.y); u[1] = pack2(a0.z, a0.w);
            u[2] = pack2(a1.x, a1.y); u[3] = pack2(a1.z, a1.w);
            B0 = __builtin_bit_cast(bf16x8, *(uint4*)u);
            u[0] = pack2(a2.x, a2.y); u[1] = pack2(a2.z, a2.w);
            u[2] = pack2(a3.x, a3.y); u[3] = pack2(a3.z, a3.w);
            B1 = __builtin_bit_cast(bf16x8, *(uint4*)u);
            unsigned z[4] = {0u, 0u, 0u, 0u};
            if (lq == 0) z[0] = pack2(np[2 * nc], np[2 * nc + 1]);
            B2 = __builtin_bit_cast(bf16x8, *(uint4*)z);
        }

        f32x4 acc[4];
        #pragma unroll
        for (int mf = 0; mf < 4; ++mf) {
            acc[mf] = (f32x4){0.f, 0.f, 0.f, 0.f};
            acc[mf] = __builtin_amdgcn_mfma_f32_16x16x32_bf16(aw[mf][0], B0, acc[mf], 0, 0, 0);
            acc[mf] = __builtin_amdgcn_mfma_f32_16x16x32_bf16(aw[mf][1], B1, acc[mf], 0, 0, 0);
            acc[mf] = __builtin_amdgcn_mfma_f32_16x16x32_bf16(aw[mf][2], B2, acc[mf], 0, 0, 0);
        }

        if (n < N) {
            unsigned short* row = SAB + (size_t)n * 256;
            #pragma unroll
            for (int mf = 0; mf < 4; ++mf) {
                uint2 u;
                u.x = pack2h(acc[mf][0] + b1v[mf].x, acc[mf][1] + b1v[mf].y);
                u.y = pack2h(acc[mf][2] + b1v[mf].z, acc[mf][3] + b1v[mf].w);
                *(uint2*)&row[wv * 64 + mf * 16 + lq * 4] = u;
            }
        }
    }
}

// ---------------------------------------------------------------------------
// k_edge_v5: barrier-free, LDS-free. Each wave owns 16 edges per group.
// (byte-identical to round-10/13 PASSING version)
// ---------------------------------------------------------------------------
__global__ __launch_bounds__(256, 3)
void k_edge_v5(const unsigned short* __restrict__ SAB,  // [N][256] fp16
               const unsigned* __restrict__ epk,        // [E] fp16 pair
               const int* __restrict__ eidx,            // flat [2E]
               const float* __restrict__ W1,
               const float* __restrict__ W2, const float* __restrict__ b2,
               float* __restrict__ agg,
               int N, int E)
{
    const int t = threadIdx.x;
    const int lane = t & 63;
    const int wv = t >> 6;
    const int lr = lane & 15;
    const int lq = lane >> 4;

    half2v wA[4][4], wB[4][4];
    #pragma unroll
    for (int ks = 0; ks < 4; ++ks)
        #pragma unroll
        for (int c = 0; c < 4; ++c) {
            const int d = ks * 32 + lq * 8 + 2 * c;
            half2v a; a[0] = (_Float16)W1[132 * 128 + d]; a[1] = (_Float16)W1[132 * 128 + d + 1];
            half2v b; b[0] = (_Float16)W1[133 * 128 + d]; b[1] = (_Float16)W1[133 * 128 + d + 1];
            wA[ks][c] = a; wB[ks][c] = b;
        }

    bf16x8 bw2[4];
    #pragma unroll
    for (int ks = 0; ks < 4; ++ks) {
        bf16x8 w;
        #pragma unroll
        for (int j = 0; j < 8; ++j) {
            const int k = ks * 32 + lq * 8 + j;
            w[j] = (short)f2bf(W2[(size_t)k * 16 + lr]);
        }
        bw2[ks] = w;
    }
    const float bias2 = b2[lr];

    const uint4* S4 = (const uint4*)SAB;
    const int nG = (E + 15) / 16;
    const int gstride = gridDim.x * 4;
    int g = blockIdx.x * 4 + wv;
    if (g >= nG) return;

    int s0, r0; unsigned ep0; int rc0[4];
    uint4 A0[4], B0[4];
    {
        const int eb = g * 16;
        const int e = eb + lr; const int ec = (e < E) ? e : (E - 1);
        s0 = eidx[ec]; r0 = eidx[E + ec]; ep0 = epk[ec];
        if (eb + 16 <= E) {
            const int4 rv = *(const int4*)&eidx[E + eb + lq * 4];
            rc0[0] = rv.x; rc0[1] = rv.y; rc0[2] = rv.z; rc0[3] = rv.w;
        } else {
            #pragma unroll
            for (int r2 = 0; r2 < 4; ++r2) {
                int e4 = eb + lq * 4 + r2;
                rc0[r2] = eidx[E + ((e4 < E) ? e4 : (E - 1))];
            }
        }
        const uint4* pa = S4 + (size_t)s0 * 32;
        const uint4* pb = S4 + (size_t)r0 * 32 + 16;
        #pragma unroll
        for (int ks = 0; ks < 4; ++ks) { A0[ks] = pa[ks * 4 + lq]; B0[ks] = pb[ks * 4 + lq]; }
    }

    for (; g < nG; g += gstride) {
        const int gn = g + gstride;
        const bool hn = gn < nG;

        int s1 = 0, r1 = 0; unsigned ep1 = 0; int rc1[4] = {0, 0, 0, 0};
        if (hn) {
            const int eb = gn * 16;
            const int e = eb + lr; const int ec = (e < E) ? e : (E - 1);
            s1 = eidx[ec]; r1 = eidx[E + ec]; ep1 = epk[ec];
            if (eb + 16 <= E) {
                const int4 rv = *(const int4*)&eidx[E + eb + lq * 4];
                rc1[0] = rv.x; rc1[1] = rv.y; rc1[2] = rv.z; rc1[3] = rv.w;
            } else {
                #pragma unroll
                for (int r2 = 0; r2 < 4; ++r2) {
                    int e4 = eb + lq * 4 + r2;
                    rc1[r2] = eidx[E + ((e4 < E) ? e4 : (E - 1))];
                }
            }
        }

        const unsigned elo = (ep0 & 0xffffu) | (ep0 << 16);
        const unsigned ehi = (ep0 >> 16) | (ep0 & 0xffff0000u);
        const half2v e0 = __builtin_bit_cast(half2v, elo);
        const half2v e1 = __builtin_bit_cast(half2v, ehi);

        bf16x8 af[4];
        #pragma unroll
        for (int ks = 0; ks < 4; ++ks) {
            unsigned w[4];
            const unsigned* ua = (const unsigned*)&A0[ks];
            const unsigned* ub = (const unsigned*)&B0[ks];
            #pragma unroll
            for (int c = 0; c < 4; ++c) {
                half2v v = __builtin_bit_cast(half2v, ua[c])
                         + __builtin_bit_cast(half2v, ub[c]);
                v = wA[ks][c] * e0 + v;
                v = wB[ks][c] * e1 + v;
                const float x0 = (float)v[0];
                const float x1 = (float)v[1];
                w[c] = cvt_pk(silu(x0), silu(x1));
            }
            af[ks] = __builtin_bit_cast(bf16x8, *(uint4*)w);
        }

        uint4 A1[4], B1[4];
        if (hn) {
            const uint4* pa = S4 + (size_t)s1 * 32;
            const uint4* pb = S4 + (size_t)r1 * 32 + 16;
            #pragma unroll
            for (int ks = 0; ks < 4; ++ks) { A1[ks] = pa[ks * 4 + lq]; B1[ks] = pb[ks * 4 + lq]; }
        }

        f32x4 acc = (f32x4){0.f, 0.f, 0.f, 0.f};
        #pragma unroll
        for (int ks = 0; ks < 4; ++ks)
            acc = __builtin_amdgcn_mfma_f32_16x16x32_bf16(af[ks], bw2[ks], acc, 0, 0, 0);

        const int eb = g * 16;
        if (eb + 16 <= E) {
            #pragma unroll
            for (int r2 = 0; r2 < 4; ++r2)
                atomicAdd(&agg[(size_t)rc0[r2] * 16 + lr], silu(acc[r2] + bias2));
        } else {
            #pragma unroll
            for (int r2 = 0; r2 < 4; ++r2)
                if (eb + lq * 4 + r2 < E)
                    atomicAdd(&agg[(size_t)rc0[r2] * 16 + lr], silu(acc[r2] + bias2));
        }

        if (hn) {
            s0 = s1; r0 = r1; ep0 = ep1;
            #pragma unroll
            for (int r2 = 0; r2 < 4; ++r2) rc0[r2] = rc1[r2];
            #pragma unroll
            for (int ks = 0; ks < 4; ++ks) { A0[ks] = A1[ks]; B0[ks] = B1[ks]; }
        }
    }
}

// ---------------------------------------------------------------------------
// k_node2h: 128-thread (2-wave) blocks, Jacobi 4 sweeps.
// (byte-identical to round-13 PASSING version)
// ---------------------------------------------------------------------------
__host__ __device__ constexpr int tix(int i, int j) {
    return (i <= j) ? (i * 8 - (i * (i + 1)) / 2 + j)
                    : (j * 8 - (j * (j + 1)) / 2 + i);
}

template <int P, int Q>
__device__ __forceinline__ void jrot(float* T, float* V) {
    const float app = T[tix(P, P)];
    const float aqq = T[tix(Q, Q)];
    const float apq = T[tix(P, Q)];

    float theta = (aqq - app) / (2.0f * apq);
    float at = fabsf(theta);
    float tt = 1.0f / (at + sqrtf(at * at + 1.0f));
    tt = (theta < 0.0f) ? -tt : tt;
    float cc = __frsqrt_rn(tt * tt + 1.0f);
    float ss = tt * cc;

    const bool skip = !(fabsf(apq) > 1e-36f);
    const float c  = skip ? 1.0f : cc;
    const float s  = skip ? 0.0f : ss;
    const float tu = skip ? 0.0f : tt;

    #pragma unroll
    for (int k = 0; k < 8; ++k) {
        if (k == P || k == Q) continue;
        const float akp = T[tix(k, P)], akq = T[tix(k, Q)];
        T[tix(k, P)] = c * akp - s * akq;
        T[tix(k, Q)] = s * akp + c * akq;
    }
    T[tix(P, P)] = app - tu * apq;
    T[tix(Q, Q)] = aqq + tu * apq;
    T[tix(P, Q)] = 0.0f;

    #pragma unroll
    for (int k = 0; k < 8; ++k) {
        const float vp = V[k * 8 + P], vq = V[k * 8 + Q];
        V[k * 8 + P] = c * vp - s * vq;
        V[k * 8 + Q] = s * vp + c * vq;
    }
}

__device__ __forceinline__ void jacobi_sweep(float* T, float* V) {
    jrot<0,1>(T,V); jrot<0,2>(T,V); jrot<0,3>(T,V); jrot<0,4>(T,V);
    jrot<0,5>(T,V); jrot<0,6>(T,V); jrot<0,7>(T,V);
    jrot<1,2>(T,V); jrot<1,3>(T,V); jrot<1,4>(T,V); jrot<1,5>(T,V);
    jrot<1,6>(T,V); jrot<1,7>(T,V);
    jrot<2,3>(T,V); jrot<2,4>(T,V); jrot<2,5>(T,V); jrot<2,6>(T,V);
    jrot<2,7>(T,V);
    jrot<3,4>(T,V); jrot<3,5>(T,V); jrot<3,6>(T,V); jrot<3,7>(T,V);
    jrot<4,5>(T,V); jrot<4,6>(T,V); jrot<4,7>(T,V);
    jrot<5,6>(T,V); jrot<5,7>(T,V);
    jrot<6,7>(T,V);
}

#define CSWAP(a, b)                                                          \
    {                                                                        \
        bool sw = eig[a] > eig[b];                                           \
        float lo = sw ? eig[b] : eig[a];                                     \
        float hi = sw ? eig[a] : eig[b];                                     \
        eig[a] = lo; eig[b] = hi;                                            \
        _Pragma("unroll")                                                    \
        for (int k = 0; k < 8; ++k) {                                        \
            float va = V[k * 8 + a], vb = V[k * 8 + b];                      \
            V[k * 8 + a] = sw ? vb : va;                                     \
            V[k * 8 + b] = sw ? va : vb;                                     \
        }                                                                    \
    }

__global__ __launch_bounds__(128)
void k_node2h(const float* __restrict__ h_i,
              const float* __restrict__ agg,
              const float* __restrict__ W3, const float* __restrict__ b3,
              const float* __restrict__ W4, const float* __restrict__ b4,
              float* __restrict__ out, int N)
{
    __shared__ _Float16 fl[2][64][40];
    __shared__ _Float16 hl[2][16][136];
    __shared__ float    zl[2][64][8];

    const int t = threadIdx.x;
    const int lane = t & 63;
    const int wv = t >> 6;        // 0..1
    const int lr = lane & 15;
    const int lq = lane >> 4;

    const int n  = blockIdx.x * 128 + t;
    const int nc = (n < N) ? n : (N - 1);

    float T[36], V[64];
    {
        float A[64];
        const float4* src = (const float4*)(h_i + (size_t)nc * 64);
        #pragma unroll
        for (int i = 0; i < 16; ++i) ((float4*)A)[i] = src[i];
        #pragma unroll
        for (int i = 0; i < 8; ++i)
            #pragma unroll
            for (int j = 0; j < 8; ++j)
                if (i <= j) T[tix(i, j)] = A[i * 8 + j];
    }
    #pragma unroll
    for (int i = 0; i < 64; ++i) V[i] = 0.0f;
    #pragma unroll
    for (int i = 0; i < 8; ++i) V[i * 8 + i] = 1.0f;

    #pragma unroll 1
    for (int sw = 0; sw < 4; ++sw) jacobi_sweep(T, V);

    float eig[8];
    #pragma unroll
    for (int i = 0; i < 8; ++i) eig[i] = T[tix(i, i)];

    CSWAP(0,1) CSWAP(2,3) CSWAP(4,5) CSWAP(6,7)
    CSWAP(0,2) CSWAP(1,3) CSWAP(4,6) CSWAP(5,7)
    CSWAP(1,2) CSWAP(5,6)
    CSWAP(0,4) CSWAP(1,5) CSWAP(2,6) CSWAP(3,7)
    CSWAP(2,4) CSWAP(3,5)
    CSWAP(1,2) CSWAP(3,4) CSWAP(5,6)

    // W3/W4 f16 fragments
    f16x8 w3f[8];
    #pragma unroll
    for (int nf = 0; nf < 8; ++nf) {
        f16x8 w;
        #pragma unroll
        for (int j = 0; j < 8; ++j)
            w[j] = (_Float16)W3[(size_t)(lq * 8 + j) * 128 + nf * 16 + lr];
        w3f[nf] = w;
    }
    f16x8 w4f[4];
    #pragma unroll
    for (int ks = 0; ks < 4; ++ks) {
        f16x8 w;
        #pragma unroll
        for (int j = 0; j < 8; ++j)
            w[j] = (lr < 8) ? (_Float16)W4[(size_t)(ks * 32 + lq * 8 + j) * 8 + lr]
                            : (_Float16)0.0f;
        w4f[ks] = w;
    }
    float b3v[8];
    #pragma unroll
    for (int nf = 0; nf < 8; ++nf) b3v[nf] = b3[nf * 16 + lr];
    const float b4v = (lr < 8) ? b4[lr] : 0.0f;

    // feats = [agg(16) | eig(8) | 1.0 x8] -> LDS (f16)
    {
        float f[32];
        const float4* ag = (const float4*)(agg + (size_t)nc * 16);
        #pragma unroll
        for (int i = 0; i < 4; ++i) {
            float4 v = ag[i];
            f[i * 4 + 0] = v.x; f[i * 4 + 1] = v.y;
            f[i * 4 + 2] = v.z; f[i * 4 + 3] = v.w;
        }
        #pragma unroll
        for (int i = 0; i < 8; ++i) f[16 + i] = eig[i];
        #pragma unroll
        for (int i = 0; i < 8; ++i) f[24 + i] = 1.0f;

        unsigned* dst = (unsigned*)&fl[wv][lane][0];
        #pragma unroll
        for (int i = 0; i < 16; ++i) dst[i] = pack2h(f[2 * i], f[2 * i + 1]);
    }
    __syncthreads();

    #pragma unroll 1
    for (int b = 0; b < 4; ++b) {
        const f16x8 a1 = *(const f16x8*)&fl[wv][b * 16 + lr][lq * 8];
        f32x4 acc1[8];
        #pragma unroll
        for (int nf = 0; nf < 8; ++nf) {
            acc1[nf] = (f32x4){0.f, 0.f, 0.f, 0.f};
            acc1[nf] = __builtin_amdgcn_mfma_f32_16x16x32_f16(a1, w3f[nf], acc1[nf], 0, 0, 0);
        }
        #pragma unroll
        for (int nf = 0; nf < 8; ++nf)
            #pragma unroll
            for (int r2 = 0; r2 < 4; ++r2) {
                const float x = acc1[nf][r2] + b3v[nf];
                hl[wv][lq * 4 + r2][nf * 16 + lr] = (_Float16)silu(x);
            }
        __syncthreads();

        f32x4 acc2 = (f32x4){0.f, 0.f, 0.f, 0.f};
        #pragma unroll
        for (int ks = 0; ks < 4; ++ks) {
            const f16x8 a2 = *(const f16x8*)&hl[wv][lr][ks * 32 + lq * 8];
            acc2 = __builtin_amdgcn_mfma_f32_16x16x32_f16(a2, w4f[ks], acc2, 0, 0, 0);
        }
        if (lr < 8) {
            #pragma unroll
            for (int r2 = 0; r2 < 4; ++r2)
                zl[wv][b * 16 + lq * 4 + r2][lr] = acc2[r2] + b4v;
        }
        __syncthreads();
    }

    float z[8];
    {
        float4 z0 = *(const float4*)&zl[wv][lane][0];
        float4 z1 = *(const float4*)&zl[wv][lane][4];
        z[0] = z0.x; z[1] = z0.y; z[2] = z0.z; z[3] = z0.w;
        z[4] = z1.x; z[5] = z1.y; z[6] = z1.z; z[7] = z1.w;
    }
    float m = z[0];
    #pragma unroll
    for (int o = 1; o < 8; ++o) m = fmaxf(m, z[o]);
    float lam[8], den = 0.0f;
    #pragma unroll
    for (int o = 0; o < 8; ++o) { lam[o] = __expf(z[o] - m); den += lam[o]; }
    const float inv = 1.0f / den;
    #pragma unroll
    for (int o = 0; o < 8; ++o) lam[o] *= inv;

    if (n < N) {
        float* orow = out + (size_t)n * 64;
        #pragma unroll
        for (int i = 0; i < 8; ++i) {
            float si[8];
            #pragma unroll
            for (int j = 0; j < 8; ++j) si[j] = lam[j] * V[i * 8 + j];
            float r[8];
            #pragma unroll
            for (int k = 0; k < 8; ++k) {
                float sum = 0.0f;
                #pragma unroll
                for (int j = 0; j < 8; ++j) sum += si[j] * V[k * 8 + j];
                r[k] = sum;
            }
            ((float4*)orow)[i * 2 + 0] = make_float4(r[0], r[1], r[2], r[3]);
            ((float4*)orow)[i * 2 + 1] = make_float4(r[4], r[5], r[6], r[7]);
        }
    }
}

// ---------------------------------------------------------------------------
// Fallback edge kernel (round-2 style, raw fp32 inputs, needs only agg in ws)
// ---------------------------------------------------------------------------
#define CATS 168
#define HS   136
__global__ __launch_bounds__(256, 2)
void k_edge_v2(const float* __restrict__ h_i,
               const float* __restrict__ node_params,
               const float* __restrict__ edge_params,
               const float* __restrict__ W1, const float* __restrict__ b1,
               const float* __restrict__ W2, const float* __restrict__ b2,
               const int* __restrict__ eidx,
               float* __restrict__ agg,
               int N, int E)
{
    __shared__ unsigned short smem[23680];
    unsigned short* w1t = smem;
    unsigned short* w2t = smem + 128 * CATS;
    unsigned short* cat = smem;
    unsigned short* hid = smem + 64 * CATS;

    const int t = threadIdx.x;
    const int lane = t & 63;
    const int wv = t >> 6;
    const int wn = wv & 1;
    const int wm = wv >> 1;
    const int lr = lane & 15;
    const int lq = lane >> 4;

    for (int idx = t; idx < 128 * 80; idx += 256) {
        const int col = idx & 127, kp = idx >> 7;
        const int k0 = 2 * kp;
        float f0 = (k0     < 134) ? W1[(size_t)k0       * 128 + col] : 0.0f;
        float f1 = (k0 + 1 < 134) ? W1[(size_t)(k0 + 1) * 128 + col] : 0.0f;
        *(unsigned*)&w1t[col * CATS + k0] = pack2(f0, f1);
    }
    for (int idx = t; idx < 16 * 64; idx += 256) {
        const int col = idx & 15, kp = idx >> 4;
        const int k0 = 2 * kp;
        *(unsigned*)&w2t[col * HS + k0] =
            pack2(W2[(size_t)k0 * 16 + col], W2[(size_t)(k0 + 1) * 16 + col]);
    }
    __syncthreads();

    bf16x8 bw1[4][5];
    #pragma unroll
    for (int nf = 0; nf < 4; ++nf)
        #pragma unroll
        for (int ks = 0; ks < 5; ++ks)
            bw1[nf][ks] = *(const bf16x8*)&w1t[(wn * 64 + nf * 16 + lr) * CATS + ks * 32 + lq * 8];
    bf16x8 bw2[4];
    #pragma unroll
    for (int ks = 0; ks < 4; ++ks)
        bw2[ks] = *(const bf16x8*)&w2t[lr * HS + ks * 32 + lq * 8];

    float bias1[4];
    #pragma unroll
    for (int nf = 0; nf < 4; ++nf) bias1[nf] = b1[wn * 64 + nf * 16 + lr];
    const float bias2 = b2[lr];
    __syncthreads();

    const int el = t >> 2;
    const int p  = t & 3;

    const int nTiles = E / 64;
    for (int tile = blockIdx.x; tile < nTiles; tile += gridDim.x) {
        const int ebase = tile * 64;
        {
            const int eg  = ebase + el;
            const int egc = (eg < E) ? eg : (E - 1);
            const int s = eidx[egc];
            const int r = eidx[E + egc];
            const float4* hs = (const float4*)(h_i + (size_t)s * 64);
            const float4* hr = (const float4*)(h_i + (size_t)r * 64);
            unsigned short* crow = cat + el * CATS;
            #pragma unroll
            for (int m = 0; m < 8; ++m) {
                const int q = p + 4 * m;
                float4 v = (q < 16) ? hs[q] : hr[q - 16];
                uint2 u; u.x = pack2(v.x, v.y); u.y = pack2(v.z, v.w);
                *(uint2*)&crow[q * 4] = u;
            }
            if (p == 0) {
                const int i0 = eidx[2 * egc];
                const int i1 = eidx[2 * egc + 1];
                uint4 u;
                u.x = pack2(node_params[2 * s], node_params[2 * s + 1]);
                u.y = pack2(node_params[2 * r], node_params[2 * r + 1]);
                u.z = pack2(edge_params[i0], edge_params[i1]);
                u.w = 0u;
                *(uint4*)&crow[128] = u;
            } else {
                uint4 z; z.x = z.y = z.z = z.w = 0u;
                *(uint4*)&crow[136 + (p - 1) * 8] = z;
            }
        }
        __syncthreads();

        f32x4 acc[2][4];
        #pragma unroll
        for (int mf = 0; mf < 2; ++mf)
            #pragma unroll
            for (int nf = 0; nf < 4; ++nf)
                acc[mf][nf] = (f32x4){0.f, 0.f, 0.f, 0.f};

        const unsigned short* pa = cat + (wm * 32 + lr) * CATS + lq * 8;
        #pragma unroll
        for (int ks = 0; ks < 5; ++ks) {
            const bf16x8 a0 = *(const bf16x8*)(pa + ks * 32);
            const bf16x8 a1 = *(const bf16x8*)(pa + 16 * CATS + ks * 32);
            #pragma unroll
            for (int nf = 0; nf < 4; ++nf) {
                acc[0][nf] = __builtin_amdgcn_mfma_f32_16x16x32_bf16(a0, bw1[nf][ks], acc[0][nf], 0, 0, 0);
                acc[1][nf] = __builtin_amdgcn_mfma_f32_16x16x32_bf16(a1, bw1[nf][ks], acc[1][nf], 0, 0, 0);
            }
        }
        __syncthreads();

        #pragma unroll
        for (int mf = 0; mf < 2; ++mf)
            #pragma unroll
            for (int nf = 0; nf < 4; ++nf) {
                const float bb = bias1[nf];
                #pragma unroll
                for (int r2 = 0; r2 < 4; ++r2) {
                    const float x = acc[mf][nf][r2] + bb;
                    hid[(wm * 32 + mf * 16 + lq * 4 + r2) * HS + wn * 64 + nf * 16 + lr] =
                        f2bf(silu(x));
                }
            }
        __syncthreads();

        f32x4 acc2 = (f32x4){0.f, 0.f, 0.f, 0.f};
        const unsigned short* ph = hid + (wv * 16 + lr) * HS + lq * 8;
        #pragma unroll
        for (int ks = 0; ks < 4; ++ks)
            acc2 = __builtin_amdgcn_mfma_f32_16x16x32_bf16(
                *(const bf16x8*)(ph + ks * 32), bw2[ks], acc2, 0, 0, 0);

        #pragma unroll
        for (int r2 = 0; r2 < 4; ++r2) {
            const int eg2 = ebase + wv * 16 + lq * 4 + r2;
            if (eg2 < E) {
                const int rcv = eidx[E + eg2];
                const float v = silu(acc2[r2] + bias2);
                atomicAdd(&agg[(size_t)rcv * 16 + lr], v);
            }
        }
        __syncthreads();
    }
}

// ---------------------------------------------------------------------------
extern "C" void kernel_launch(void* const* d_in, const int* in_sizes, int n_in,
                              void* d_out, int out_size, void* d_ws, size_t ws_size,
                              hipStream_t stream) {
    const float* h_i  = (const float*)d_in[0];
    const float* npar = (const float*)d_in[1];
    const float* epar = (const float*)d_in[2];
    const float* W1   = (const float*)d_in[3];
    const float* b1   = (const float*)d_in[4];
    const float* W2   = (const float*)d_in[5];
    const float* b2   = (const float*)d_in[6];
    const float* W3   = (const float*)d_in[7];
    const float* b3   = (const float*)d_in[8];
    const float* W4   = (const float*)d_in[9];
    const float* b4   = (const float*)d_in[10];
    const int*   eidx = (const int*)d_in[11];

    const int N = in_sizes[0] / 64;
    const int E = in_sizes[11] / 2;

    // workspace layout: agg | SAB(fp16 N x 256) | epk
    const size_t aggB = (size_t)N * 16 * sizeof(float);
    size_t off = (aggB + 255) & ~(size_t)255;
    const size_t sabOff = off;                  off += (size_t)N * 256 * 2;
    off = (off + 255) & ~(size_t)255;
    const size_t epkOff = off;                  off += (size_t)E * 4;
    const size_t need = off;

    float* agg = (float*)d_ws;

    if (ws_size >= need) {
        unsigned short* SAB = (unsigned short*)((char*)d_ws + sabOff);
        unsigned* epk = (unsigned*)((char*)d_ws + epkOff);

        k_pre2<<<PRE_MFMA_B + PRE_AUX_B, 256, 0, stream>>>(
            h_i, npar, epar, eidx, W1, b1, SAB, epk, agg, N, E);
        k_edge_v5<<<2048, 256, 0, stream>>>(SAB, epk, eidx, W1, W2, b2,
                                            agg, N, E);
    } else {
        (void)hipMemsetAsync(agg, 0, aggB, stream);
        int blocks = E / 64;
        if (blocks > 768) blocks = 768;
        k_edge_v2<<<blocks, 256, 0, stream>>>(h_i, npar, epar, W1, b1, W2, b2,
                                              eidx, agg, N, E);
    }
    k_node2h<<<(N + 127) / 128, 128, 0, stream>>>(h_i, agg, W3, b3, W4, b4,
                                                  (float*)d_out, N);
}